// Round 6
// baseline (228.038 us; speedup 1.0000x reference)
//
#include <hip/hip_runtime.h>
#include <hip/hip_cooperative_groups.h>
#include <math.h>

namespace cg = cooperative_groups;

typedef unsigned short ushortT;
typedef __bf16 bf16x8 __attribute__((ext_vector_type(8)));
typedef float  f32x4  __attribute__((ext_vector_type(4)));

// grade of each multivector component (blade order: 1,e1,e2,e3,e12,e13,e23,e123)
__constant__ int GRADEc[8] = {0,1,1,1,2,2,2,3};

// Compacted slot maps: zero-weight padding slots removed.
__constant__ int CMAPc[8][7] = {
  {0, 8, 9,10,11, 0, 0},
  {1,12,13,14,15,16,17},
  {2,18,19,20,21,22,23},
  {3,24,25,26,27,28,29},
  {4,30,31,32,33,34,35},
  {5,36,37,38,39,40,41},
  {6,42,43,44,45,46,47},
  {7,48,49,50,51, 0, 0}};
__constant__ int WMAPc[8][7] = {
  {0, 4, 8,14,20, 0, 0},
  {1, 5, 9,10,15,16,21},
  {1, 5, 9,10,15,16,21},
  {1, 5, 9,10,15,16,21},
  {2, 6,11,12,17,18,22},
  {2, 6,11,12,17,18,22},
  {2, 6,11,12,17,18,22},
  {3, 7,13,19,23, 0, 0}};
// outer split-K=2 slot ranges per (j, ks2): j=0,7 have 5 slots {3,2}; others 7 {4,3}
__constant__ int SSTART2c[8][2] = {{0,3},{0,4},{0,4},{0,4},{0,4},{0,4},{0,4},{0,3}};
__constant__ int SCOUNT2c[8][2] = {{3,2},{4,3},{4,3},{4,3},{4,3},{4,3},{4,3},{3,2}};

__device__ __forceinline__ ushortT f2bf(float f) {
  unsigned int u = __float_as_uint(f);
  unsigned int r = (u + 0x7fffu + ((u >> 16) & 1u)) >> 16;
  return (ushortT)r;
}

// async global->LDS 16B DMA: dest = wave-uniform base + lane*16 (linear), source per-lane.
#define GLOAD_LDS16(gsrc, ldst) \
  __builtin_amdgcn_global_load_lds((const __attribute__((address_space(1))) unsigned int*)(gsrc), \
                                   (__attribute__((address_space(3))) unsigned int*)(ldst), 16, 0, 0)

#define WAITVM(N) asm volatile("s_waitcnt vmcnt(" #N ")" ::: "memory")
#define SCHEDB()  __builtin_amdgcn_sched_barrier(0)
#define RAWBAR()  do { SCHEDB(); __builtin_amdgcn_s_barrier(); asm volatile("" ::: "memory"); SCHEDB(); } while (0)

// ================= single cooperative kernel: prep -> right_feat -> gemm -> merge ==========
__global__ __launch_bounds__(512, 2) void k_fused(
    const float* __restrict__ x, const float* __restrict__ w_right,
    const float* __restrict__ w_left, const float* __restrict__ bleft,
    const float* __restrict__ norm_a, const float* __restrict__ gp,
    float* __restrict__ out,
    ushortT* __restrict__ XH, ushortT* __restrict__ XL,
    ushortT* __restrict__ WH, ushortT* __restrict__ WL,
    ushortT* __restrict__ FT2b, ushortT* __restrict__ WT2b,
    float* __restrict__ outP) {
  cg::grid_group grid = cg::this_grid();
  __shared__ __align__(16) ushortT lds[49152];   // 96 KB, reused by every phase
  const int bid = blockIdx.x;
  const int tid = threadIdx.x;

  // ---------------- phase 1: prep (grid-stride over 1536 virtual blocks of 256) ----------------
  {
    #pragma unroll
    for (int k = 0; k < 3; ++k) {
      int u  = k * 131072 + bid * 512 + tid;
      int vb = u >> 8, vt = u & 255;
      if (vb < 256) {            // WT2b[w][m][n], coalesced gp/w_left reads
        const int m = vb, n = vt;
        float4 wl = *(const float4*)(w_left + m * 1024 + n * 4);
        float g[20];
        const float4* gp4 = (const float4*)(gp + m * 5120 + n * 20);
        #pragma unroll
        for (int q = 0; q < 5; ++q) {
          float4 v = gp4[q];
          g[q * 4 + 0] = v.x; g[q * 4 + 1] = v.y; g[q * 4 + 2] = v.z; g[q * 4 + 3] = v.w;
        }
        const int base = m * 256 + n;
        WT2b[0 * 65536 + base] = f2bf(wl.x);
        WT2b[1 * 65536 + base] = f2bf(wl.y);
        WT2b[2 * 65536 + base] = f2bf(wl.z);
        WT2b[3 * 65536 + base] = f2bf(wl.w);
        #pragma unroll
        for (int p = 0; p < 20; ++p)
          WT2b[(4 + p) * 65536 + base] = f2bf(g[p]);
      } else if (vb < 1280) {    // x split: XH/XL[i][b][m]
        int b = vb - 256;
        const float4* xp = (const float4*)(x + b * 2048 + vt * 8);
        float4 a = xp[0], c = xp[1];
        float v[8] = {a.x, a.y, a.z, a.w, c.x, c.y, c.z, c.w};
        #pragma unroll
        for (int i = 0; i < 8; ++i) {
          ushortT h = f2bf(v[i]);
          float hf = __uint_as_float(((unsigned int)h) << 16);
          XH[i * 262144 + b * 256 + vt] = h;
          XL[i * 262144 + b * 256 + vt] = f2bf(v[i] - hf);
        }
      } else {                   // w_right split: WH/WL[g][n][m]
        int n = vb - 1280;
        float4 w = *(const float4*)(w_right + n * 1024 + vt * 4);
        float v[4] = {w.x, w.y, w.z, w.w};
        #pragma unroll
        for (int g2 = 0; g2 < 4; ++g2) {
          ushortT h = f2bf(v[g2]);
          float hf = __uint_as_float(((unsigned int)h) << 16);
          WH[g2 * 65536 + n * 256 + vt] = h;
          WL[g2 * 65536 + n * 256 + vt] = f2bf(v[g2] - hf);
        }
      }
    }
  }
  grid.sync();

  // ---------------- phase 2: right-linear MFMA (3-term bf16 split) + normalize + features ----
  {
    const int lin = bid;
    const int rr  = lin & 7;
    const int q   = lin >> 3;
    const int xb  = q & 7;                 // n-tile 0..7
    const int yb  = (q >> 3) * 8 + rr;     // b-tile 0..31
    const int n0 = xb * 32;
    const int b0 = yb * 32;
    const int t    = tid;
    const int wave = t >> 6;          // = i plane
    const int lane = t & 63;
    const int i    = wave;
    const int g    = GRADEc[i];
    const int lrow = lane & 15, lkg = lane >> 4;
    const int srow = lane >> 2;
    const int sseg = lane & 3;

    const ushortT* Asrc_h = XH + i * 262144 + b0 * 256;
    const ushortT* Asrc_l = XL + i * 262144 + b0 * 256;
    const int bg = wave >> 1;
    const ushortT* Bsrc = ((wave & 1) ? WL : WH) + bg * 65536 + n0 * 256;

    f32x4 acc[2][2];
    #pragma unroll
    for (int r = 0; r < 2; ++r)
      #pragma unroll
      for (int c = 0; c < 2; ++c)
        acc[r][c] = (f32x4){0.f, 0.f, 0.f, 0.f};

    auto STAGE = [&](int k0, int buf) {
      ushortT* base = lds + buf * 24576;
      #pragma unroll
      for (int q2 = 0; q2 < 2; ++q2) {
        int row = q2 * 16 + srow;
        int slog = sseg ^ ((row >> 1) & 3);
        GLOAD_LDS16(Asrc_h + row * 256 + k0 + slog * 8, base + i * 1024 + q2 * 512);
        GLOAD_LDS16(Asrc_l + row * 256 + k0 + slog * 8, base + 8192 + i * 1024 + q2 * 512);
        GLOAD_LDS16(Bsrc   + row * 256 + k0 + slog * 8,
                    base + 16384 + (wave & 1) * 4096 + bg * 1024 + q2 * 512);
      }
    };

    auto COMPUTE = [&](int buf) {
      const ushortT* base = lds + buf * 24576;
      bf16x8 afh[2], afl[2], bfh[2], bfl[2];
      #pragma unroll
      for (int r = 0; r < 2; ++r) {
        int row = r * 16 + lrow;
        int po = row * 32 + (lkg ^ ((row >> 1) & 3)) * 8;
        afh[r] = *(const bf16x8*)(base + i * 1024 + po);
        afl[r] = *(const bf16x8*)(base + 8192 + i * 1024 + po);
      }
      #pragma unroll
      for (int c = 0; c < 2; ++c) {
        int row = c * 16 + lrow;
        int po = row * 32 + (lkg ^ ((row >> 1) & 3)) * 8;
        bfh[c] = *(const bf16x8*)(base + 16384 + g * 1024 + po);
        bfl[c] = *(const bf16x8*)(base + 20480 + g * 1024 + po);
      }
      #pragma unroll
      for (int r = 0; r < 2; ++r)
        #pragma unroll
        for (int c = 0; c < 2; ++c) {
          acc[r][c] = __builtin_amdgcn_mfma_f32_16x16x32_bf16(afh[r], bfh[c], acc[r][c], 0, 0, 0);
          acc[r][c] = __builtin_amdgcn_mfma_f32_16x16x32_bf16(afl[r], bfh[c], acc[r][c], 0, 0, 0);
          acc[r][c] = __builtin_amdgcn_mfma_f32_16x16x32_bf16(afh[r], bfl[c], acc[r][c], 0, 0, 0);
        }
    };

    STAGE(0, 0);
    int cur = 0;
    for (int tc = 0; tc < 8; ++tc) {
      if (tc < 7) { STAGE((tc + 1) * 32, cur ^ 1); SCHEDB(); WAITVM(6); }
      else        { WAITVM(0); }
      RAWBAR();
      COMPUTE(cur);
      if (tc < 7) RAWBAR();
      cur ^= 1;
    }

    // dump y tiles to LDS: y_lds[i][32][33] fp32
    float* yl = (float*)lds;
    #pragma unroll
    for (int r = 0; r < 2; ++r)
      #pragma unroll
      for (int c = 0; c < 2; ++c)
        #pragma unroll
        for (int e = 0; e < 4; ++e) {
          int row = r * 16 + lkg * 4 + e;
          int col = c * 16 + lrow;
          yl[i * 1056 + row * 33 + col] = acc[r][c][e];
        }
    __syncthreads();

    #pragma unroll
    for (int e2 = 0; e2 < 2; ++e2) {
      int el  = t + e2 * 512;
      int row = el >> 5, col = el & 31;
      int b = b0 + row, n = n0 + col;
      float y[8];
      #pragma unroll
      for (int q2 = 0; q2 < 8; ++q2) y[q2] = yl[q2 * 1056 + row * 33 + col];
      const float4* xp = (const float4*)(x + b * 2048 + n * 8);
      float4 x01 = xp[0], x23 = xp[1];
      float xv[8] = {x01.x, x01.y, x01.z, x01.w, x23.x, x23.y, x23.z, x23.w};
      float4 na = *(const float4*)(norm_a + n * 4);
      float nav[4] = {na.x, na.y, na.z, na.w};
      float nr[4];
      nr[0] = fabsf(y[0]);
      nr[1] = sqrtf(y[1]*y[1] + y[2]*y[2] + y[3]*y[3]);
      nr[2] = sqrtf(y[4]*y[4] + y[5]*y[5] + y[6]*y[6]);
      nr[3] = fabsf(y[7]);
      float inv[4];
      #pragma unroll
      for (int gg = 0; gg < 4; ++gg) {
        float s = 1.0f / (1.0f + expf(-nav[gg]));
        inv[gg] = 1.0f / (s * (nr[gg] - 1.0f) + 1.0f + 1e-6f);
      }
      float r[8];
      r[0] = y[0]*inv[0];
      r[1] = y[1]*inv[1]; r[2] = y[2]*inv[1]; r[3] = y[3]*inv[1];
      r[4] = y[4]*inv[2]; r[5] = y[5]*inv[2]; r[6] = y[6]*inv[2];
      r[7] = y[7]*inv[3];

      float F[52];
      F[8]  = xv[0]*r[0];
      F[9]  = xv[1]*r[1] + xv[2]*r[2] + xv[3]*r[3];
      F[10] = -(xv[4]*r[4] + xv[5]*r[5] + xv[6]*r[6]);
      F[11] = -xv[7]*r[7];
      F[12] = xv[0]*r[1];
      F[13] = xv[1]*r[0];
      F[14] = -(xv[2]*r[4] + xv[3]*r[5]);
      F[15] = xv[4]*r[2] + xv[5]*r[3];
      F[16] = -xv[6]*r[7];
      F[17] = -xv[7]*r[6];
      F[18] = xv[0]*r[2];
      F[19] = xv[2]*r[0];
      F[20] = xv[1]*r[4] - xv[3]*r[6];
      F[21] = -xv[4]*r[1] + xv[6]*r[3];
      F[22] = xv[5]*r[7];
      F[23] = xv[7]*r[5];
      F[24] = xv[0]*r[3];
      F[25] = xv[3]*r[0];
      F[26] = xv[1]*r[5] + xv[2]*r[6];
      F[27] = -(xv[5]*r[1] + xv[6]*r[2]);
      F[28] = -xv[4]*r[7];
      F[29] = -xv[7]*r[4];
      F[30] = xv[0]*r[4];
      F[31] = xv[1]*r[2] - xv[2]*r[1];
      F[32] = xv[3]*r[7];
      F[33] = xv[4]*r[0];
      F[34] = -xv[5]*r[6] + xv[6]*r[5];
      F[35] = xv[7]*r[3];
      F[36] = xv[0]*r[5];
      F[37] = xv[1]*r[3] - xv[3]*r[1];
      F[38] = -xv[2]*r[7];
      F[39] = xv[5]*r[0];
      F[40] = xv[4]*r[6] - xv[6]*r[4];
      F[41] = -xv[7]*r[2];
      F[42] = xv[0]*r[6];
      F[43] = xv[2]*r[3] - xv[3]*r[2];
      F[44] = xv[1]*r[7];
      F[45] = xv[6]*r[0];
      F[46] = -xv[4]*r[5] + xv[5]*r[4];
      F[47] = xv[7]*r[1];
      F[48] = xv[0]*r[7];
      F[49] = xv[1]*r[6] - xv[2]*r[5] + xv[3]*r[4];
      F[50] = xv[4]*r[3] - xv[5]*r[2] + xv[6]*r[1];
      F[51] = xv[7]*r[0];

      #pragma unroll
      for (int c = 8; c < 52; ++c)
        FT2b[c * 262144 + b * 256 + n] = f2bf(F[c]);
    }
  }
  grid.sync();

  // ---------------- phase 3: main GEMM (MFMA bf16), in-block kk split + outer split-K=2 ------
  {
    const int lin = bid;                 // 0..255
    const int rr  = lin & 7;
    const int q   = lin >> 3;            // 0..31
    const int ix  = q & 15;              // 16 blocks per (j,ks2) group
    const int z   = rr + 8 * (q >> 4);   // group id 0..15
    const int j   = z >> 1;
    const int ks  = z & 1;
    const int m0  = (ix & 1) * 128;
    const int b0  = (ix >> 1) * 128;
    const int t    = tid;
    const int wave = t >> 6;             // 0..7
    const int kkg  = wave >> 2;          // kk-half this wave consumes
    const int w4   = wave & 3;
    const int lane = t & 63;
    const int wb   = (w4 & 1) * 64;
    const int wm   = (w4 >> 1) * 64;
    const int lrow = lane & 15;
    const int lkg  = lane >> 4;
    const int srow = lane >> 3;          // 0..7 rows within staging instr
    const int sseg = lane & 7;           // phys 16B seg (8 per 128B row)

    f32x4 acc[4][4];
    #pragma unroll
    for (int r = 0; r < 4; ++r)
      #pragma unroll
      for (int c = 0; c < 4; ++c)
        acc[r][c] = (f32x4){0.f, 0.f, 0.f, 0.f};

    const int sstart = SSTART2c[j][ks];
    const int nt     = SCOUNT2c[j][ks] * 4;  // chunks of K=64

    auto STAGE = [&](int tch, int buf) {
      int slot = sstart + (tch >> 2);
      int k0   = (tch & 3) << 6;
      const ushortT* Ap = ((slot == 0) ? (XH + j * 262144)
                                       : (FT2b + CMAPc[j][slot] * 262144)) + b0 * 256;
      const ushortT* Bp = WT2b + WMAPc[j][slot] * 65536 + m0 * 256;
      #pragma unroll
      for (int q2 = 0; q2 < 2; ++q2) {
        int idx = wave * 2 + q2;         // staging instr 0..15
        int row = idx * 8 + srow;        // 0..127
        int slog = sseg ^ (row & 7);
        GLOAD_LDS16(Ap + row * 256 + k0 + slog * 8, lds + buf * 8192 + idx * 512);
        GLOAD_LDS16(Bp + row * 256 + k0 + slog * 8, lds + 16384 + buf * 8192 + idx * 512);
      }
    };

    STAGE(0, 0);
    int cur = 0;
    for (int tc = 0; tc < nt; ++tc) {
      if (tc + 1 < nt) { STAGE(tc + 1, cur ^ 1); SCHEDB(); WAITVM(4); }
      else             { WAITVM(0); }
      RAWBAR();
      const ushortT* sA = lds + cur * 8192;
      const ushortT* sB = lds + 16384 + cur * 8192;
      bf16x8 af[4], bf[4];
      #pragma unroll
      for (int r = 0; r < 4; ++r) {
        int row = wb + r * 16 + lrow;
        af[r] = *(const bf16x8*)(sA + row * 64 + (((kkg * 4 + lkg) ^ (row & 7)) * 8));
      }
      #pragma unroll
      for (int c = 0; c < 4; ++c) {
        int row = wm + c * 16 + lrow;
        bf[c] = *(const bf16x8*)(sB + row * 64 + (((kkg * 4 + lkg) ^ (row & 7)) * 8));
      }
      #pragma unroll
      for (int r = 0; r < 4; ++r)
        #pragma unroll
        for (int c = 0; c < 4; ++c)
          acc[r][c] = __builtin_amdgcn_mfma_f32_16x16x32_bf16(af[r], bf[c], acc[r][c], 0, 0, 0);
      if (tc + 1 < nt) RAWBAR();
      cur ^= 1;
    }

    // reduce kk-group partials: group 1 dumps acc to LDS, group 0 adds and stores.
    __syncthreads();
    float* fl = (float*)lds;             // 64KB, w4-disjoint 64x64 tiles
    if (kkg == 1) {
      #pragma unroll
      for (int r = 0; r < 4; ++r)
        #pragma unroll
        for (int c = 0; c < 4; ++c)
          #pragma unroll
          for (int e = 0; e < 4; ++e) {
            int row = r * 16 + lkg * 4 + e;
            int col = c * 16 + lrow;
            fl[w4 * 4096 + row * 64 + col] = acc[r][c][e];
          }
    }
    __syncthreads();
    if (kkg == 0) {
      float* oj = outP + (ks * 8 + j) * 262144;
      #pragma unroll
      for (int r = 0; r < 4; ++r) {
        #pragma unroll
        for (int c = 0; c < 4; ++c) {
          #pragma unroll
          for (int e = 0; e < 4; ++e) {
            int row = r * 16 + lkg * 4 + e;
            int col = c * 16 + lrow;
            float v = acc[r][c][e] + fl[w4 * 4096 + row * 64 + col];
            oj[(b0 + wb + row) * 256 + m0 + wm + col] = v;
          }
        }
      }
    }
  }
  grid.sync();

  // ---------------- phase 4: merge: out[b][m][j] = (sum_ks2 outP + bias_j) / sqrt(2) ---------
  {
    const int gtid = bid * 512 + tid;
    if (gtid < 65536) {
      const int t4 = gtid * 4;             // base idx over b*m = 262144
      const int m  = t4 & 255;
      const float sc = 0.7071067811865475f;
      float o[4][8];
      #pragma unroll
      for (int jj = 0; jj < 8; ++jj) {
        float4 s = make_float4(0.f, 0.f, 0.f, 0.f);
        #pragma unroll
        for (int p = 0; p < 2; ++p) {
          float4 v = *(const float4*)(outP + (p * 8 + jj) * 262144 + t4);
          s.x += v.x; s.y += v.y; s.z += v.z; s.w += v.w;
        }
        o[0][jj] = s.x; o[1][jj] = s.y; o[2][jj] = s.z; o[3][jj] = s.w;
      }
      #pragma unroll
      for (int q = 0; q < 4; ++q) {
        float ov[8];
        #pragma unroll
        for (int jj = 0; jj < 8; ++jj) ov[jj] = o[q][jj];
        ov[0] += bleft[m + q];
        float4 v0 = make_float4(ov[0]*sc, ov[1]*sc, ov[2]*sc, ov[3]*sc);
        float4 v1 = make_float4(ov[4]*sc, ov[5]*sc, ov[6]*sc, ov[7]*sc);
        *(float4*)(out + (t4 + q) * 8)     = v0;
        *(float4*)(out + (t4 + q) * 8 + 4) = v1;
      }
    }
  }
}

extern "C" void kernel_launch(void* const* d_in, const int* in_sizes, int n_in,
                              void* d_out, int out_size, void* d_ws, size_t ws_size,
                              hipStream_t stream) {
  const float* x       = (const float*)d_in[0];
  const float* w_right = (const float*)d_in[1];
  const float* w_left  = (const float*)d_in[2];
  const float* b_left  = (const float*)d_in[3];
  const float* norm_a  = (const float*)d_in[4];
  const float* gp      = (const float*)d_in[5];
  float* out = (float*)d_out;
  float* W   = (float*)d_ws;

  // ws layout (float offsets)
  float*   outP = W;                          //  4,194,304 floats (2 split-K partial planes)
  ushortT* XH   = (ushortT*)(W + 4194304);    //  2,097,152 ushort (1,048,576 floats)
  ushortT* XL   = (ushortT*)(W + 5242880);    //  2,097,152 ushort
  ushortT* WH   = (ushortT*)(W + 6291456);    //    262,144 ushort (  131,072 floats)
  ushortT* WL   = (ushortT*)(W + 6422528);    //    262,144 ushort
  ushortT* FT2b = (ushortT*)(W + 6553600);    // 13,631,488 ushort (6,815,744 floats)
  ushortT* WT2b = (ushortT*)(W + 13369344);   //  1,572,864 ushort (  786,432 floats)

  void* args[] = { (void*)&x, (void*)&w_right, (void*)&w_left, (void*)&b_left,
                   (void*)&norm_a, (void*)&gp, (void*)&out,
                   (void*)&XH, (void*)&XL, (void*)&WH, (void*)&WL,
                   (void*)&FT2b, (void*)&WT2b, (void*)&outP };
  hipLaunchCooperativeKernel((const void*)k_fused, dim3(256), dim3(512), args, 0, stream);
}

// Round 7
// 110.329 us; speedup vs baseline: 2.0669x; 2.0669x over previous
//
#include <hip/hip_runtime.h>
#include <math.h>

typedef unsigned short ushortT;
typedef __bf16 bf16x8 __attribute__((ext_vector_type(8)));
typedef float  f32x4  __attribute__((ext_vector_type(4)));

// grade of each multivector component (blade order: 1,e1,e2,e3,e12,e13,e23,e123)
__constant__ int GRADEc[8] = {0,1,1,1,2,2,2,3};

// Compacted slot maps: zero-weight padding slots removed.
__constant__ int CMAPc[8][7] = {
  {0, 8, 9,10,11, 0, 0},
  {1,12,13,14,15,16,17},
  {2,18,19,20,21,22,23},
  {3,24,25,26,27,28,29},
  {4,30,31,32,33,34,35},
  {5,36,37,38,39,40,41},
  {6,42,43,44,45,46,47},
  {7,48,49,50,51, 0, 0}};
__constant__ int WMAPc[8][7] = {
  {0, 4, 8,14,20, 0, 0},
  {1, 5, 9,10,15,16,21},
  {1, 5, 9,10,15,16,21},
  {1, 5, 9,10,15,16,21},
  {2, 6,11,12,17,18,22},
  {2, 6,11,12,17,18,22},
  {2, 6,11,12,17,18,22},
  {3, 7,13,19,23, 0, 0}};
// outer split-K=2 slot ranges per (j, ks2): j=0,7 have 5 slots {3,2}; others 7 {4,3}
__constant__ int SSTART2c[8][2] = {{0,3},{0,4},{0,4},{0,4},{0,4},{0,4},{0,4},{0,3}};
__constant__ int SCOUNT2c[8][2] = {{3,2},{4,3},{4,3},{4,3},{4,3},{4,3},{4,3},{3,2}};

__device__ __forceinline__ ushortT f2bf(float f) {
  unsigned int u = __float_as_uint(f);
  unsigned int r = (u + 0x7fffu + ((u >> 16) & 1u)) >> 16;
  return (ushortT)r;
}

// async global->LDS 16B DMA: dest = wave-uniform base + lane*16 (linear), source per-lane.
#define GLOAD_LDS16(gsrc, ldst) \
  __builtin_amdgcn_global_load_lds((const __attribute__((address_space(1))) unsigned int*)(gsrc), \
                                   (__attribute__((address_space(3))) unsigned int*)(ldst), 16, 0, 0)

#define WAITVM(N) asm volatile("s_waitcnt vmcnt(" #N ")" ::: "memory")
#define SCHEDB()  __builtin_amdgcn_sched_barrier(0)
#define RAWBAR()  do { SCHEDB(); __builtin_amdgcn_s_barrier(); asm volatile("" ::: "memory"); SCHEDB(); } while (0)

// ---------------- fused prep: WT2b build (coalesced gp) + x hi/lo split + w_right hi/lo split
__global__ void k_prep(const float* __restrict__ x, const float* __restrict__ w_right,
                       const float* __restrict__ w_left, const float* __restrict__ gp,
                       ushortT* __restrict__ XH, ushortT* __restrict__ XL,
                       ushortT* __restrict__ WH, ushortT* __restrict__ WL,
                       ushortT* __restrict__ WT2b) {
  const int bid = blockIdx.x;
  const int tid = threadIdx.x;
  if (bid < 256) {             // WT2b[w][m][n], one block per m: fully coalesced gp/w_left reads
    const int m = bid, n = tid;
    float4 wl = *(const float4*)(w_left + m * 1024 + n * 4);
    float g[20];
    const float4* gp4 = (const float4*)(gp + m * 5120 + n * 20);
    #pragma unroll
    for (int q = 0; q < 5; ++q) {
      float4 v = gp4[q];
      g[q * 4 + 0] = v.x; g[q * 4 + 1] = v.y; g[q * 4 + 2] = v.z; g[q * 4 + 3] = v.w;
    }
    const int base = m * 256 + n;
    WT2b[0 * 65536 + base] = f2bf(wl.x);
    WT2b[1 * 65536 + base] = f2bf(wl.y);
    WT2b[2 * 65536 + base] = f2bf(wl.z);
    WT2b[3 * 65536 + base] = f2bf(wl.w);
    #pragma unroll
    for (int p = 0; p < 20; ++p)
      WT2b[(4 + p) * 65536 + base] = f2bf(g[p]);
  } else if (bid < 1280) {     // x split: XH/XL[i][b][m]
    int b = bid - 256;
    const float4* xp = (const float4*)(x + b * 2048 + tid * 8);
    float4 a = xp[0], c = xp[1];
    float v[8] = {a.x, a.y, a.z, a.w, c.x, c.y, c.z, c.w};
    #pragma unroll
    for (int i = 0; i < 8; ++i) {
      ushortT h = f2bf(v[i]);
      float hf = __uint_as_float(((unsigned int)h) << 16);
      XH[i * 262144 + b * 256 + tid] = h;
      XL[i * 262144 + b * 256 + tid] = f2bf(v[i] - hf);
    }
  } else {                     // w_right split: WH/WL[g][n][m]
    int n = bid - 1280;
    float4 w = *(const float4*)(w_right + n * 1024 + tid * 4);
    float v[4] = {w.x, w.y, w.z, w.w};
    #pragma unroll
    for (int g2 = 0; g2 < 4; ++g2) {
      ushortT h = f2bf(v[g2]);
      float hf = __uint_as_float(((unsigned int)h) << 16);
      WH[g2 * 65536 + n * 256 + tid] = h;
      WL[g2 * 65536 + n * 256 + tid] = f2bf(v[g2] - hf);
    }
  }
}

// ---------------- fused right-linear (MFMA, 3-term bf16 split) + normalize + features ------
// 1-D grid 256, XCD-chunked. Counted-vmcnt double-buffer (T4).
__global__ __launch_bounds__(512) void k_right_feat(const ushortT* __restrict__ XH,
                                                    const ushortT* __restrict__ XL,
                                                    const ushortT* __restrict__ WH,
                                                    const ushortT* __restrict__ WL,
                                                    const float* __restrict__ x,
                                                    const float* __restrict__ norm_a,
                                                    ushortT* __restrict__ FT2b) {
  const int lin = blockIdx.x;
  const int rr  = lin & 7;
  const int q   = lin >> 3;
  const int xb  = q & 7;                 // n-tile 0..7
  const int yb  = (q >> 3) * 8 + rr;     // b-tile 0..31
  const int n0 = xb * 32;
  const int b0 = yb * 32;
  __shared__ __align__(16) ushortT lds[49152];   // 96 KB
  const int t    = threadIdx.x;
  const int wave = t >> 6;          // = i plane
  const int lane = t & 63;
  const int i    = wave;
  const int g    = GRADEc[i];
  const int lrow = lane & 15, lkg = lane >> 4;
  const int srow = lane >> 2;
  const int sseg = lane & 3;

  const ushortT* Asrc_h = XH + i * 262144 + b0 * 256;
  const ushortT* Asrc_l = XL + i * 262144 + b0 * 256;
  const int bg = wave >> 1;
  const ushortT* Bsrc = ((wave & 1) ? WL : WH) + bg * 65536 + n0 * 256;

  f32x4 acc[2][2];
  #pragma unroll
  for (int r = 0; r < 2; ++r)
    #pragma unroll
    for (int c = 0; c < 2; ++c)
      acc[r][c] = (f32x4){0.f, 0.f, 0.f, 0.f};

  auto STAGE = [&](int k0, int buf) {
    ushortT* base = lds + buf * 24576;
    #pragma unroll
    for (int q2 = 0; q2 < 2; ++q2) {
      int row = q2 * 16 + srow;
      int slog = sseg ^ ((row >> 1) & 3);
      GLOAD_LDS16(Asrc_h + row * 256 + k0 + slog * 8, base + i * 1024 + q2 * 512);
      GLOAD_LDS16(Asrc_l + row * 256 + k0 + slog * 8, base + 8192 + i * 1024 + q2 * 512);
      GLOAD_LDS16(Bsrc   + row * 256 + k0 + slog * 8,
                  base + 16384 + (wave & 1) * 4096 + bg * 1024 + q2 * 512);
    }
  };

  auto COMPUTE = [&](int buf) {
    const ushortT* base = lds + buf * 24576;
    bf16x8 afh[2], afl[2], bfh[2], bfl[2];
    #pragma unroll
    for (int r = 0; r < 2; ++r) {
      int row = r * 16 + lrow;
      int po = row * 32 + (lkg ^ ((row >> 1) & 3)) * 8;
      afh[r] = *(const bf16x8*)(base + i * 1024 + po);
      afl[r] = *(const bf16x8*)(base + 8192 + i * 1024 + po);
    }
    #pragma unroll
    for (int c = 0; c < 2; ++c) {
      int row = c * 16 + lrow;
      int po = row * 32 + (lkg ^ ((row >> 1) & 3)) * 8;
      bfh[c] = *(const bf16x8*)(base + 16384 + g * 1024 + po);
      bfl[c] = *(const bf16x8*)(base + 20480 + g * 1024 + po);
    }
    #pragma unroll
    for (int r = 0; r < 2; ++r)
      #pragma unroll
      for (int c = 0; c < 2; ++c) {
        acc[r][c] = __builtin_amdgcn_mfma_f32_16x16x32_bf16(afh[r], bfh[c], acc[r][c], 0, 0, 0);
        acc[r][c] = __builtin_amdgcn_mfma_f32_16x16x32_bf16(afl[r], bfh[c], acc[r][c], 0, 0, 0);
        acc[r][c] = __builtin_amdgcn_mfma_f32_16x16x32_bf16(afh[r], bfl[c], acc[r][c], 0, 0, 0);
      }
  };

  STAGE(0, 0);
  int cur = 0;
  for (int tc = 0; tc < 8; ++tc) {
    if (tc < 7) { STAGE((tc + 1) * 32, cur ^ 1); SCHEDB(); WAITVM(6); }
    else        { WAITVM(0); }
    RAWBAR();
    COMPUTE(cur);
    if (tc < 7) RAWBAR();
    cur ^= 1;
  }

  // dump y tiles to LDS: y_lds[i][32][33] fp32
  float* yl = (float*)lds;
  #pragma unroll
  for (int r = 0; r < 2; ++r)
    #pragma unroll
    for (int c = 0; c < 2; ++c)
      #pragma unroll
      for (int e = 0; e < 4; ++e) {
        int row = r * 16 + lkg * 4 + e;
        int col = c * 16 + lrow;
        yl[i * 1056 + row * 33 + col] = acc[r][c][e];
      }
  __syncthreads();

  #pragma unroll
  for (int e2 = 0; e2 < 2; ++e2) {
    int el  = t + e2 * 512;
    int row = el >> 5, col = el & 31;
    int b = b0 + row, n = n0 + col;
    float y[8];
    #pragma unroll
    for (int q2 = 0; q2 < 8; ++q2) y[q2] = yl[q2 * 1056 + row * 33 + col];
    const float4* xp = (const float4*)(x + b * 2048 + n * 8);
    float4 x01 = xp[0], x23 = xp[1];
    float xv[8] = {x01.x, x01.y, x01.z, x01.w, x23.x, x23.y, x23.z, x23.w};
    float4 na = *(const float4*)(norm_a + n * 4);
    float nav[4] = {na.x, na.y, na.z, na.w};
    float nr[4];
    nr[0] = fabsf(y[0]);
    nr[1] = sqrtf(y[1]*y[1] + y[2]*y[2] + y[3]*y[3]);
    nr[2] = sqrtf(y[4]*y[4] + y[5]*y[5] + y[6]*y[6]);
    nr[3] = fabsf(y[7]);
    float inv[4];
    #pragma unroll
    for (int gg = 0; gg < 4; ++gg) {
      float s = 1.0f / (1.0f + expf(-nav[gg]));
      inv[gg] = 1.0f / (s * (nr[gg] - 1.0f) + 1.0f + 1e-6f);
    }
    float r[8];
    r[0] = y[0]*inv[0];
    r[1] = y[1]*inv[1]; r[2] = y[2]*inv[1]; r[3] = y[3]*inv[1];
    r[4] = y[4]*inv[2]; r[5] = y[5]*inv[2]; r[6] = y[6]*inv[2];
    r[7] = y[7]*inv[3];

    float F[52];
    F[8]  = xv[0]*r[0];
    F[9]  = xv[1]*r[1] + xv[2]*r[2] + xv[3]*r[3];
    F[10] = -(xv[4]*r[4] + xv[5]*r[5] + xv[6]*r[6]);
    F[11] = -xv[7]*r[7];
    F[12] = xv[0]*r[1];
    F[13] = xv[1]*r[0];
    F[14] = -(xv[2]*r[4] + xv[3]*r[5]);
    F[15] = xv[4]*r[2] + xv[5]*r[3];
    F[16] = -xv[6]*r[7];
    F[17] = -xv[7]*r[6];
    F[18] = xv[0]*r[2];
    F[19] = xv[2]*r[0];
    F[20] = xv[1]*r[4] - xv[3]*r[6];
    F[21] = -xv[4]*r[1] + xv[6]*r[3];
    F[22] = xv[5]*r[7];
    F[23] = xv[7]*r[5];
    F[24] = xv[0]*r[3];
    F[25] = xv[3]*r[0];
    F[26] = xv[1]*r[5] + xv[2]*r[6];
    F[27] = -(xv[5]*r[1] + xv[6]*r[2]);
    F[28] = -xv[4]*r[7];
    F[29] = -xv[7]*r[4];
    F[30] = xv[0]*r[4];
    F[31] = xv[1]*r[2] - xv[2]*r[1];
    F[32] = xv[3]*r[7];
    F[33] = xv[4]*r[0];
    F[34] = -xv[5]*r[6] + xv[6]*r[5];
    F[35] = xv[7]*r[3];
    F[36] = xv[0]*r[5];
    F[37] = xv[1]*r[3] - xv[3]*r[1];
    F[38] = -xv[2]*r[7];
    F[39] = xv[5]*r[0];
    F[40] = xv[4]*r[6] - xv[6]*r[4];
    F[41] = -xv[7]*r[2];
    F[42] = xv[0]*r[6];
    F[43] = xv[2]*r[3] - xv[3]*r[2];
    F[44] = xv[1]*r[7];
    F[45] = xv[6]*r[0];
    F[46] = -xv[4]*r[5] + xv[5]*r[4];
    F[47] = xv[7]*r[1];
    F[48] = xv[0]*r[7];
    F[49] = xv[1]*r[6] - xv[2]*r[5] + xv[3]*r[4];
    F[50] = xv[4]*r[3] - xv[5]*r[2] + xv[6]*r[1];
    F[51] = xv[7]*r[0];

    #pragma unroll
    for (int c = 8; c < 52; ++c)
      FT2b[c * 262144 + b * 256 + n] = f2bf(F[c]);
  }
}

// ---------------- main GEMM (MFMA bf16): outP[ks2][j][b][m] partials ----------
// 512 threads (8 waves), tile 128x128. Wave-group kkg = wave>>2 consumes kk-half of each
// K=64 chunk; groups' accs LDS-reduced at end. Outer split-K=2 -> outP 16MB.
// 1-D grid 256, XCD-chunked (16 blocks per (j,ks2) group on one XCD).
// Counted-vmcnt double-buffer: WAITVM(4) steady state, 0 only on last chunk.
__global__ __launch_bounds__(512) void k_gemm_mfma(const ushortT* __restrict__ XH,
                                                   const ushortT* __restrict__ FT2b,
                                                   const ushortT* __restrict__ WT2b,
                                                   float* __restrict__ outP) {
  const int lin = blockIdx.x;          // 0..255
  const int rr  = lin & 7;
  const int q   = lin >> 3;            // 0..31
  const int ix  = q & 15;              // 16 blocks per (j,ks2) group
  const int z   = rr + 8 * (q >> 4);   // group id 0..15
  const int j   = z >> 1;
  const int ks  = z & 1;
  const int m0  = (ix & 1) * 128;
  const int b0  = (ix >> 1) * 128;
  // 2 bufs: sA at buf*8192, sB at 16384 + buf*8192 (ushort units) = 64 KB total
  __shared__ __align__(16) ushortT lds[32768];
  const int t    = threadIdx.x;
  const int wave = t >> 6;             // 0..7
  const int kkg  = wave >> 2;          // kk-half this wave consumes
  const int w4   = wave & 3;
  const int lane = t & 63;
  const int wb   = (w4 & 1) * 64;
  const int wm   = (w4 >> 1) * 64;
  const int lrow = lane & 15;
  const int lkg  = lane >> 4;
  const int srow = lane >> 3;          // 0..7 rows within staging instr
  const int sseg = lane & 7;           // phys 16B seg (8 per 128B row)

  f32x4 acc[4][4];
  #pragma unroll
  for (int r = 0; r < 4; ++r)
    #pragma unroll
    for (int c = 0; c < 4; ++c)
      acc[r][c] = (f32x4){0.f, 0.f, 0.f, 0.f};

  const int sstart = SSTART2c[j][ks];
  const int nt     = SCOUNT2c[j][ks] * 4;  // chunks of K=64

  auto STAGE = [&](int tch, int buf) {
    int slot = sstart + (tch >> 2);
    int k0   = (tch & 3) << 6;
    const ushortT* Ap = ((slot == 0) ? (XH + j * 262144)
                                     : (FT2b + CMAPc[j][slot] * 262144)) + b0 * 256;
    const ushortT* Bp = WT2b + WMAPc[j][slot] * 65536 + m0 * 256;
    #pragma unroll
    for (int q2 = 0; q2 < 2; ++q2) {
      int idx = wave * 2 + q2;         // staging instr 0..15
      int row = idx * 8 + srow;        // 0..127
      int slog = sseg ^ (row & 7);
      GLOAD_LDS16(Ap + row * 256 + k0 + slog * 8, lds + buf * 8192 + idx * 512);
      GLOAD_LDS16(Bp + row * 256 + k0 + slog * 8, lds + 16384 + buf * 8192 + idx * 512);
    }
  };

  STAGE(0, 0);
  int cur = 0;
  for (int tc = 0; tc < nt; ++tc) {
    if (tc + 1 < nt) { STAGE(tc + 1, cur ^ 1); SCHEDB(); WAITVM(4); }
    else             { WAITVM(0); }
    RAWBAR();
    const ushortT* sA = lds + cur * 8192;
    const ushortT* sB = lds + 16384 + cur * 8192;
    bf16x8 af[4], bf[4];
    #pragma unroll
    for (int r = 0; r < 4; ++r) {
      int row = wb + r * 16 + lrow;
      af[r] = *(const bf16x8*)(sA + row * 64 + (((kkg * 4 + lkg) ^ (row & 7)) * 8));
    }
    #pragma unroll
    for (int c = 0; c < 4; ++c) {
      int row = wm + c * 16 + lrow;
      bf[c] = *(const bf16x8*)(sB + row * 64 + (((kkg * 4 + lkg) ^ (row & 7)) * 8));
    }
    #pragma unroll
    for (int r = 0; r < 4; ++r)
      #pragma unroll
      for (int c = 0; c < 4; ++c)
        acc[r][c] = __builtin_amdgcn_mfma_f32_16x16x32_bf16(af[r], bf[c], acc[r][c], 0, 0, 0);
    if (tc + 1 < nt) RAWBAR();
    cur ^= 1;
  }

  // reduce kk-group partials: group 1 dumps acc to LDS, group 0 adds.
  __syncthreads();
  float* fl = (float*)lds;             // 16384 floats = 64KB, w4-disjoint 64x64 tiles
  if (kkg == 1) {
    #pragma unroll
    for (int r = 0; r < 4; ++r)
      #pragma unroll
      for (int c = 0; c < 4; ++c)
        #pragma unroll
        for (int e = 0; e < 4; ++e) {
          int row = r * 16 + lkg * 4 + e;
          int col = c * 16 + lrow;
          fl[w4 * 4096 + row * 64 + col] = acc[r][c][e];
        }
  }
  __syncthreads();
  if (kkg == 0) {
    float* oj = outP + (ks * 8 + j) * 262144;
    #pragma unroll
    for (int r = 0; r < 4; ++r) {
      #pragma unroll
      for (int c = 0; c < 4; ++c) {
        #pragma unroll
        for (int e = 0; e < 4; ++e) {
          int row = r * 16 + lkg * 4 + e;
          int col = c * 16 + lrow;
          float v = acc[r][c][e] + fl[w4 * 4096 + row * 64 + col];
          oj[(b0 + wb + row) * 256 + m0 + wm + col] = v;
        }
      }
    }
  }
}

// ---------------- merge: out[b][m][j] = (sum_ks2 outP[ks2][j][b][m] + bias_j) / sqrt(2) -----
__global__ void k_merge(const float* __restrict__ outP, const float* __restrict__ bleft,
                        float* __restrict__ out) {
  const int t4 = (blockIdx.x * 256 + threadIdx.x) * 4;   // base idx over b*m = 262144
  const int m  = t4 & 255;
  const float sc = 0.7071067811865475f;
  float o[4][8];
  #pragma unroll
  for (int jj = 0; jj < 8; ++jj) {
    float4 s = make_float4(0.f, 0.f, 0.f, 0.f);
    #pragma unroll
    for (int p = 0; p < 2; ++p) {
      float4 v = *(const float4*)(outP + (p * 8 + jj) * 262144 + t4);
      s.x += v.x; s.y += v.y; s.z += v.z; s.w += v.w;
    }
    o[0][jj] = s.x; o[1][jj] = s.y; o[2][jj] = s.z; o[3][jj] = s.w;
  }
  #pragma unroll
  for (int q = 0; q < 4; ++q) {
    float ov[8];
    #pragma unroll
    for (int jj = 0; jj < 8; ++jj) ov[jj] = o[q][jj];
    ov[0] += bleft[m + q];
    float4 v0 = make_float4(ov[0]*sc, ov[1]*sc, ov[2]*sc, ov[3]*sc);
    float4 v1 = make_float4(ov[4]*sc, ov[5]*sc, ov[6]*sc, ov[7]*sc);
    *(float4*)(out + (t4 + q) * 8)     = v0;
    *(float4*)(out + (t4 + q) * 8 + 4) = v1;
  }
}

extern "C" void kernel_launch(void* const* d_in, const int* in_sizes, int n_in,
                              void* d_out, int out_size, void* d_ws, size_t ws_size,
                              hipStream_t stream) {
  const float* x       = (const float*)d_in[0];
  const float* w_right = (const float*)d_in[1];
  const float* w_left  = (const float*)d_in[2];
  const float* b_left  = (const float*)d_in[3];
  const float* norm_a  = (const float*)d_in[4];
  const float* gp      = (const float*)d_in[5];
  float* out = (float*)d_out;
  float* W   = (float*)d_ws;

  // ws layout (float offsets)
  float*   outP = W;                          //  4,194,304 floats (2 split-K partial planes)
  ushortT* XH   = (ushortT*)(W + 4194304);    //  2,097,152 ushort (1,048,576 floats)
  ushortT* XL   = (ushortT*)(W + 5242880);    //  2,097,152 ushort
  ushortT* WH   = (ushortT*)(W + 6291456);    //    262,144 ushort (  131,072 floats)
  ushortT* WL   = (ushortT*)(W + 6422528);    //    262,144 ushort
  ushortT* FT2b = (ushortT*)(W + 6553600);    // 13,631,488 ushort (6,815,744 floats)
  ushortT* WT2b = (ushortT*)(W + 13369344);   //  1,572,864 ushort (  786,432 floats)

  k_prep<<<1536, 256, 0, stream>>>(x, w_right, w_left, gp, XH, XL, WH, WL, WT2b);
  k_right_feat<<<256, 512, 0, stream>>>(XH, XL, WH, WL, x, norm_a, FT2b);
  k_gemm_mfma<<<256, 512, 0, stream>>>(XH, FT2b, WT2b, outP);
  k_merge<<<256, 256, 0, stream>>>(outP, b_left, out);
}

// Round 8
// 109.022 us; speedup vs baseline: 2.0917x; 1.0120x over previous
//
#include <hip/hip_runtime.h>
#include <math.h>

typedef unsigned short ushortT;
typedef __bf16 bf16x8 __attribute__((ext_vector_type(8)));
typedef float  f32x4  __attribute__((ext_vector_type(4)));

// grade of each multivector component (blade order: 1,e1,e2,e3,e12,e13,e23,e123)
__constant__ int GRADEc[8] = {0,1,1,1,2,2,2,3};

// Compacted slot maps: zero-weight padding slots removed.
__constant__ int CMAPc[8][7] = {
  {0, 8, 9,10,11, 0, 0},
  {1,12,13,14,15,16,17},
  {2,18,19,20,21,22,23},
  {3,24,25,26,27,28,29},
  {4,30,31,32,33,34,35},
  {5,36,37,38,39,40,41},
  {6,42,43,44,45,46,47},
  {7,48,49,50,51, 0, 0}};
__constant__ int WMAPc[8][7] = {
  {0, 4, 8,14,20, 0, 0},
  {1, 5, 9,10,15,16,21},
  {1, 5, 9,10,15,16,21},
  {1, 5, 9,10,15,16,21},
  {2, 6,11,12,17,18,22},
  {2, 6,11,12,17,18,22},
  {2, 6,11,12,17,18,22},
  {3, 7,13,19,23, 0, 0}};
// outer split-K=2 slot ranges per (j, ks2): j=0,7 have 5 slots {3,2}; others 7 {4,3}
__constant__ int SSTART2c[8][2] = {{0,3},{0,4},{0,4},{0,4},{0,4},{0,4},{0,4},{0,3}};
__constant__ int SCOUNT2c[8][2] = {{3,2},{4,3},{4,3},{4,3},{4,3},{4,3},{4,3},{3,2}};

__device__ __forceinline__ ushortT f2bf(float f) {
  unsigned int u = __float_as_uint(f);
  unsigned int r = (u + 0x7fffu + ((u >> 16) & 1u)) >> 16;
  return (ushortT)r;
}

// async global->LDS 16B DMA: dest = wave-uniform base + lane*16 (linear), source per-lane.
#define GLOAD_LDS16(gsrc, ldst) \
  __builtin_amdgcn_global_load_lds((const __attribute__((address_space(1))) unsigned int*)(gsrc), \
                                   (__attribute__((address_space(3))) unsigned int*)(ldst), 16, 0, 0)

#define WAITVM(N) asm volatile("s_waitcnt vmcnt(" #N ")" ::: "memory")
#define SCHEDB()  __builtin_amdgcn_sched_barrier(0)
#define RAWBAR()  do { SCHEDB(); __builtin_amdgcn_s_barrier(); asm volatile("" ::: "memory"); SCHEDB(); } while (0)

// ---------------- fused prep: WT2b build (coalesced gp) + x hi/lo split + w_right hi/lo split
__global__ void k_prep(const float* __restrict__ x, const float* __restrict__ w_right,
                       const float* __restrict__ w_left, const float* __restrict__ gp,
                       ushortT* __restrict__ XH, ushortT* __restrict__ XL,
                       ushortT* __restrict__ WH, ushortT* __restrict__ WL,
                       ushortT* __restrict__ WT2b) {
  const int bid = blockIdx.x;
  const int tid = threadIdx.x;
  if (bid < 256) {             // WT2b[w][m][n], one block per m: fully coalesced gp/w_left reads
    const int m = bid, n = tid;
    float4 wl = *(const float4*)(w_left + m * 1024 + n * 4);
    float g[20];
    const float4* gp4 = (const float4*)(gp + m * 5120 + n * 20);
    #pragma unroll
    for (int q = 0; q < 5; ++q) {
      float4 v = gp4[q];
      g[q * 4 + 0] = v.x; g[q * 4 + 1] = v.y; g[q * 4 + 2] = v.z; g[q * 4 + 3] = v.w;
    }
    const int base = m * 256 + n;
    WT2b[0 * 65536 + base] = f2bf(wl.x);
    WT2b[1 * 65536 + base] = f2bf(wl.y);
    WT2b[2 * 65536 + base] = f2bf(wl.z);
    WT2b[3 * 65536 + base] = f2bf(wl.w);
    #pragma unroll
    for (int p = 0; p < 20; ++p)
      WT2b[(4 + p) * 65536 + base] = f2bf(g[p]);
  } else if (bid < 1280) {     // x split: XH/XL[i][b][m]
    int b = bid - 256;
    const float4* xp = (const float4*)(x + b * 2048 + tid * 8);
    float4 a = xp[0], c = xp[1];
    float v[8] = {a.x, a.y, a.z, a.w, c.x, c.y, c.z, c.w};
    #pragma unroll
    for (int i = 0; i < 8; ++i) {
      ushortT h = f2bf(v[i]);
      float hf = __uint_as_float(((unsigned int)h) << 16);
      XH[i * 262144 + b * 256 + tid] = h;
      XL[i * 262144 + b * 256 + tid] = f2bf(v[i] - hf);
    }
  } else {                     // w_right split: WH/WL[g][n][m]
    int n = bid - 1280;
    float4 w = *(const float4*)(w_right + n * 1024 + tid * 4);
    float v[4] = {w.x, w.y, w.z, w.w};
    #pragma unroll
    for (int g2 = 0; g2 < 4; ++g2) {
      ushortT h = f2bf(v[g2]);
      float hf = __uint_as_float(((unsigned int)h) << 16);
      WH[g2 * 65536 + n * 256 + tid] = h;
      WL[g2 * 65536 + n * 256 + tid] = f2bf(v[g2] - hf);
    }
  }
}

// ---------------- fused right-linear (MFMA, 3-term bf16 split) + normalize + features ------
// 1-D grid 256, XCD-chunked. Counted-vmcnt double-buffer (T4). Unchanged from R5/R7.
__global__ __launch_bounds__(512) void k_right_feat(const ushortT* __restrict__ XH,
                                                    const ushortT* __restrict__ XL,
                                                    const ushortT* __restrict__ WH,
                                                    const ushortT* __restrict__ WL,
                                                    const float* __restrict__ x,
                                                    const float* __restrict__ norm_a,
                                                    ushortT* __restrict__ FT2b) {
  const int lin = blockIdx.x;
  const int rr  = lin & 7;
  const int q   = lin >> 3;
  const int xb  = q & 7;                 // n-tile 0..7
  const int yb  = (q >> 3) * 8 + rr;     // b-tile 0..31
  const int n0 = xb * 32;
  const int b0 = yb * 32;
  __shared__ __align__(16) ushortT lds[49152];   // 96 KB
  const int t    = threadIdx.x;
  const int wave = t >> 6;          // = i plane
  const int lane = t & 63;
  const int i    = wave;
  const int g    = GRADEc[i];
  const int lrow = lane & 15, lkg = lane >> 4;
  const int srow = lane >> 2;
  const int sseg = lane & 3;

  const ushortT* Asrc_h = XH + i * 262144 + b0 * 256;
  const ushortT* Asrc_l = XL + i * 262144 + b0 * 256;
  const int bg = wave >> 1;
  const ushortT* Bsrc = ((wave & 1) ? WL : WH) + bg * 65536 + n0 * 256;

  f32x4 acc[2][2];
  #pragma unroll
  for (int r = 0; r < 2; ++r)
    #pragma unroll
    for (int c = 0; c < 2; ++c)
      acc[r][c] = (f32x4){0.f, 0.f, 0.f, 0.f};

  auto STAGE = [&](int k0, int buf) {
    ushortT* base = lds + buf * 24576;
    #pragma unroll
    for (int q2 = 0; q2 < 2; ++q2) {
      int row = q2 * 16 + srow;
      int slog = sseg ^ ((row >> 1) & 3);
      GLOAD_LDS16(Asrc_h + row * 256 + k0 + slog * 8, base + i * 1024 + q2 * 512);
      GLOAD_LDS16(Asrc_l + row * 256 + k0 + slog * 8, base + 8192 + i * 1024 + q2 * 512);
      GLOAD_LDS16(Bsrc   + row * 256 + k0 + slog * 8,
                  base + 16384 + (wave & 1) * 4096 + bg * 1024 + q2 * 512);
    }
  };

  auto COMPUTE = [&](int buf) {
    const ushortT* base = lds + buf * 24576;
    bf16x8 afh[2], afl[2], bfh[2], bfl[2];
    #pragma unroll
    for (int r = 0; r < 2; ++r) {
      int row = r * 16 + lrow;
      int po = row * 32 + (lkg ^ ((row >> 1) & 3)) * 8;
      afh[r] = *(const bf16x8*)(base + i * 1024 + po);
      afl[r] = *(const bf16x8*)(base + 8192 + i * 1024 + po);
    }
    #pragma unroll
    for (int c = 0; c < 2; ++c) {
      int row = c * 16 + lrow;
      int po = row * 32 + (lkg ^ ((row >> 1) & 3)) * 8;
      bfh[c] = *(const bf16x8*)(base + 16384 + g * 1024 + po);
      bfl[c] = *(const bf16x8*)(base + 20480 + g * 1024 + po);
    }
    #pragma unroll
    for (int r = 0; r < 2; ++r)
      #pragma unroll
      for (int c = 0; c < 2; ++c) {
        acc[r][c] = __builtin_amdgcn_mfma_f32_16x16x32_bf16(afh[r], bfh[c], acc[r][c], 0, 0, 0);
        acc[r][c] = __builtin_amdgcn_mfma_f32_16x16x32_bf16(afl[r], bfh[c], acc[r][c], 0, 0, 0);
        acc[r][c] = __builtin_amdgcn_mfma_f32_16x16x32_bf16(afh[r], bfl[c], acc[r][c], 0, 0, 0);
      }
  };

  STAGE(0, 0);
  int cur = 0;
  for (int tc = 0; tc < 8; ++tc) {
    if (tc < 7) { STAGE((tc + 1) * 32, cur ^ 1); SCHEDB(); WAITVM(6); }
    else        { WAITVM(0); }
    RAWBAR();
    COMPUTE(cur);
    if (tc < 7) RAWBAR();
    cur ^= 1;
  }

  // dump y tiles to LDS: y_lds[i][32][33] fp32
  float* yl = (float*)lds;
  #pragma unroll
  for (int r = 0; r < 2; ++r)
    #pragma unroll
    for (int c = 0; c < 2; ++c)
      #pragma unroll
      for (int e = 0; e < 4; ++e) {
        int row = r * 16 + lkg * 4 + e;
        int col = c * 16 + lrow;
        yl[i * 1056 + row * 33 + col] = acc[r][c][e];
      }
  __syncthreads();

  #pragma unroll
  for (int e2 = 0; e2 < 2; ++e2) {
    int el  = t + e2 * 512;
    int row = el >> 5, col = el & 31;
    int b = b0 + row, n = n0 + col;
    float y[8];
    #pragma unroll
    for (int q2 = 0; q2 < 8; ++q2) y[q2] = yl[q2 * 1056 + row * 33 + col];
    const float4* xp = (const float4*)(x + b * 2048 + n * 8);
    float4 x01 = xp[0], x23 = xp[1];
    float xv[8] = {x01.x, x01.y, x01.z, x01.w, x23.x, x23.y, x23.z, x23.w};
    float4 na = *(const float4*)(norm_a + n * 4);
    float nav[4] = {na.x, na.y, na.z, na.w};
    float nr[4];
    nr[0] = fabsf(y[0]);
    nr[1] = sqrtf(y[1]*y[1] + y[2]*y[2] + y[3]*y[3]);
    nr[2] = sqrtf(y[4]*y[4] + y[5]*y[5] + y[6]*y[6]);
    nr[3] = fabsf(y[7]);
    float inv[4];
    #pragma unroll
    for (int gg = 0; gg < 4; ++gg) {
      float s = 1.0f / (1.0f + expf(-nav[gg]));
      inv[gg] = 1.0f / (s * (nr[gg] - 1.0f) + 1.0f + 1e-6f);
    }
    float r[8];
    r[0] = y[0]*inv[0];
    r[1] = y[1]*inv[1]; r[2] = y[2]*inv[1]; r[3] = y[3]*inv[1];
    r[4] = y[4]*inv[2]; r[5] = y[5]*inv[2]; r[6] = y[6]*inv[2];
    r[7] = y[7]*inv[3];

    float F[52];
    F[8]  = xv[0]*r[0];
    F[9]  = xv[1]*r[1] + xv[2]*r[2] + xv[3]*r[3];
    F[10] = -(xv[4]*r[4] + xv[5]*r[5] + xv[6]*r[6]);
    F[11] = -xv[7]*r[7];
    F[12] = xv[0]*r[1];
    F[13] = xv[1]*r[0];
    F[14] = -(xv[2]*r[4] + xv[3]*r[5]);
    F[15] = xv[4]*r[2] + xv[5]*r[3];
    F[16] = -xv[6]*r[7];
    F[17] = -xv[7]*r[6];
    F[18] = xv[0]*r[2];
    F[19] = xv[2]*r[0];
    F[20] = xv[1]*r[4] - xv[3]*r[6];
    F[21] = -xv[4]*r[1] + xv[6]*r[3];
    F[22] = xv[5]*r[7];
    F[23] = xv[7]*r[5];
    F[24] = xv[0]*r[3];
    F[25] = xv[3]*r[0];
    F[26] = xv[1]*r[5] + xv[2]*r[6];
    F[27] = -(xv[5]*r[1] + xv[6]*r[2]);
    F[28] = -xv[4]*r[7];
    F[29] = -xv[7]*r[4];
    F[30] = xv[0]*r[4];
    F[31] = xv[1]*r[2] - xv[2]*r[1];
    F[32] = xv[3]*r[7];
    F[33] = xv[4]*r[0];
    F[34] = -xv[5]*r[6] + xv[6]*r[5];
    F[35] = xv[7]*r[3];
    F[36] = xv[0]*r[5];
    F[37] = xv[1]*r[3] - xv[3]*r[1];
    F[38] = -xv[2]*r[7];
    F[39] = xv[5]*r[0];
    F[40] = xv[4]*r[6] - xv[6]*r[4];
    F[41] = -xv[7]*r[2];
    F[42] = xv[0]*r[6];
    F[43] = xv[2]*r[3] - xv[3]*r[2];
    F[44] = xv[1]*r[7];
    F[45] = xv[6]*r[0];
    F[46] = -xv[4]*r[5] + xv[5]*r[4];
    F[47] = xv[7]*r[1];
    F[48] = xv[0]*r[7];
    F[49] = xv[1]*r[6] - xv[2]*r[5] + xv[3]*r[4];
    F[50] = xv[4]*r[3] - xv[5]*r[2] + xv[6]*r[1];
    F[51] = xv[7]*r[0];

    #pragma unroll
    for (int c = 8; c < 52; ++c)
      FT2b[c * 262144 + b * 256 + n] = f2bf(F[c]);
  }
}

// ---------------- main GEMM (MFMA bf16): outP[ks2][j][b][m] partials ----------
// 512 threads (8 waves), tile 128x128, in-block kk-split (kkg=wave>>2) + outer split-K=2.
// TRIPLE-buffered staging, ONE barrier per K=64 chunk: with bufs mod 3, the buffer
// STAGE(t+2) overwrites (= buf (t-1)%3) was last read at iter t-1, and iter t's single
// barrier already orders that read before the overwrite. Prefetch depth 2 (8 loads in
// flight); WAITVM(4) retires exactly chunk t before the barrier. LDS 96KB, 1 block/CU.
__global__ __launch_bounds__(512) void k_gemm_mfma(const ushortT* __restrict__ XH,
                                                   const ushortT* __restrict__ FT2b,
                                                   const ushortT* __restrict__ WT2b,
                                                   float* __restrict__ outP) {
  const int lin = blockIdx.x;          // 0..255
  const int rr  = lin & 7;
  const int q   = lin >> 3;            // 0..31
  const int ix  = q & 15;              // 16 blocks per (j,ks2) group
  const int z   = rr + 8 * (q >> 4);   // group id 0..15
  const int j   = z >> 1;
  const int ks  = z & 1;
  const int m0  = (ix & 1) * 128;
  const int b0  = (ix >> 1) * 128;
  // 3 bufs x 32KB: sA at buf*16384, sB at buf*16384 + 8192 (ushort units) = 96 KB total
  __shared__ __align__(16) ushortT lds[49152];
  const int t    = threadIdx.x;
  const int wave = t >> 6;             // 0..7
  const int kkg  = wave >> 2;          // kk-half this wave consumes
  const int w4   = wave & 3;
  const int lane = t & 63;
  const int wb   = (w4 & 1) * 64;
  const int wm   = (w4 >> 1) * 64;
  const int lrow = lane & 15;
  const int lkg  = lane >> 4;
  const int srow = lane >> 3;          // 0..7 rows within staging instr
  const int sseg = lane & 7;           // phys 16B seg (8 per 128B row)

  f32x4 acc[4][4];
  #pragma unroll
  for (int r = 0; r < 4; ++r)
    #pragma unroll
    for (int c = 0; c < 4; ++c)
      acc[r][c] = (f32x4){0.f, 0.f, 0.f, 0.f};

  const int sstart = SSTART2c[j][ks];
  const int nt     = SCOUNT2c[j][ks] * 4;  // chunks of K=64 (8..16)

  auto STAGE = [&](int tch, int buf) {
    int slot = sstart + (tch >> 2);
    int k0   = (tch & 3) << 6;
    const ushortT* Ap = ((slot == 0) ? (XH + j * 262144)
                                     : (FT2b + CMAPc[j][slot] * 262144)) + b0 * 256;
    const ushortT* Bp = WT2b + WMAPc[j][slot] * 65536 + m0 * 256;
    #pragma unroll
    for (int q2 = 0; q2 < 2; ++q2) {
      int idx = wave * 2 + q2;         // staging instr 0..15
      int row = idx * 8 + srow;        // 0..127
      int slog = sseg ^ (row & 7);
      GLOAD_LDS16(Ap + row * 256 + k0 + slog * 8, lds + buf * 16384 + idx * 512);
      GLOAD_LDS16(Bp + row * 256 + k0 + slog * 8, lds + buf * 16384 + 8192 + idx * 512);
    }
  };

  STAGE(0, 0);
  STAGE(1, 1);
  for (int tc = 0; tc < nt; ++tc) {
    if (tc + 1 < nt) { WAITVM(4); }    // chunk tc done; tc+1's 4 loads stay in flight
    else             { WAITVM(0); }
    RAWBAR();                          // all waves see chunk tc in LDS
    if (tc + 2 < nt) { STAGE(tc + 2, (tc + 2) % 3); SCHEDB(); }
    const ushortT* sA = lds + (tc % 3) * 16384;
    const ushortT* sB = sA + 8192;
    bf16x8 af[4], bf[4];
    #pragma unroll
    for (int r = 0; r < 4; ++r) {
      int row = wb + r * 16 + lrow;
      af[r] = *(const bf16x8*)(sA + row * 64 + (((kkg * 4 + lkg) ^ (row & 7)) * 8));
    }
    #pragma unroll
    for (int c = 0; c < 4; ++c) {
      int row = wm + c * 16 + lrow;
      bf[c] = *(const bf16x8*)(sB + row * 64 + (((kkg * 4 + lkg) ^ (row & 7)) * 8));
    }
    #pragma unroll
    for (int r = 0; r < 4; ++r)
      #pragma unroll
      for (int c = 0; c < 4; ++c)
        acc[r][c] = __builtin_amdgcn_mfma_f32_16x16x32_bf16(af[r], bf[c], acc[r][c], 0, 0, 0);
  }

  // reduce kk-group partials: group 1 dumps acc to LDS, group 0 adds.
  __syncthreads();
  float* fl = (float*)lds;             // 16384 floats = 64KB, w4-disjoint 64x64 tiles
  if (kkg == 1) {
    #pragma unroll
    for (int r = 0; r < 4; ++r)
      #pragma unroll
      for (int c = 0; c < 4; ++c)
        #pragma unroll
        for (int e = 0; e < 4; ++e) {
          int row = r * 16 + lkg * 4 + e;
          int col = c * 16 + lrow;
          fl[w4 * 4096 + row * 64 + col] = acc[r][c][e];
        }
  }
  __syncthreads();
  if (kkg == 0) {
    float* oj = outP + (ks * 8 + j) * 262144;
    #pragma unroll
    for (int r = 0; r < 4; ++r) {
      #pragma unroll
      for (int c = 0; c < 4; ++c) {
        #pragma unroll
        for (int e = 0; e < 4; ++e) {
          int row = r * 16 + lkg * 4 + e;
          int col = c * 16 + lrow;
          float v = acc[r][c][e] + fl[w4 * 4096 + row * 64 + col];
          oj[(b0 + wb + row) * 256 + m0 + wm + col] = v;
        }
      }
    }
  }
}

// ---------------- merge: out[b][m][j] = (sum_ks2 outP[ks2][j][b][m] + bias_j) / sqrt(2) -----
__global__ void k_merge(const float* __restrict__ outP, const float* __restrict__ bleft,
                        float* __restrict__ out) {
  const int t4 = (blockIdx.x * 256 + threadIdx.x) * 4;   // base idx over b*m = 262144
  const int m  = t4 & 255;
  const float sc = 0.7071067811865475f;
  float o[4][8];
  #pragma unroll
  for (int jj = 0; jj < 8; ++jj) {
    float4 s = make_float4(0.f, 0.f, 0.f, 0.f);
    #pragma unroll
    for (int p = 0; p < 2; ++p) {
      float4 v = *(const float4*)(outP + (p * 8 + jj) * 262144 + t4);
      s.x += v.x; s.y += v.y; s.z += v.z; s.w += v.w;
    }
    o[0][jj] = s.x; o[1][jj] = s.y; o[2][jj] = s.z; o[3][jj] = s.w;
  }
  #pragma unroll
  for (int q = 0; q < 4; ++q) {
    float ov[8];
    #pragma unroll
    for (int jj = 0; jj < 8; ++jj) ov[jj] = o[q][jj];
    ov[0] += bleft[m + q];
    float4 v0 = make_float4(ov[0]*sc, ov[1]*sc, ov[2]*sc, ov[3]*sc);
    float4 v1 = make_float4(ov[4]*sc, ov[5]*sc, ov[6]*sc, ov[7]*sc);
    *(float4*)(out + (t4 + q) * 8)     = v0;
    *(float4*)(out + (t4 + q) * 8 + 4) = v1;
  }
}

extern "C" void kernel_launch(void* const* d_in, const int* in_sizes, int n_in,
                              void* d_out, int out_size, void* d_ws, size_t ws_size,
                              hipStream_t stream) {
  const float* x       = (const float*)d_in[0];
  const float* w_right = (const float*)d_in[1];
  const float* w_left  = (const float*)d_in[2];
  const float* b_left  = (const float*)d_in[3];
  const float* norm_a  = (const float*)d_in[4];
  const float* gp      = (const float*)d_in[5];
  float* out = (float*)d_out;
  float* W   = (float*)d_ws;

  // ws layout (float offsets)
  float*   outP = W;                          //  4,194,304 floats (2 split-K partial planes)
  ushortT* XH   = (ushortT*)(W + 4194304);    //  2,097,152 ushort (1,048,576 floats)
  ushortT* XL   = (ushortT*)(W + 5242880);    //  2,097,152 ushort
  ushortT* WH   = (ushortT*)(W + 6291456);    //    262,144 ushort (  131,072 floats)
  ushortT* WL   = (ushortT*)(W + 6422528);    //    262,144 ushort
  ushortT* FT2b = (ushortT*)(W + 6553600);    // 13,631,488 ushort (6,815,744 floats)
  ushortT* WT2b = (ushortT*)(W + 13369344);   //  1,572,864 ushort (  786,432 floats)

  k_prep<<<1536, 256, 0, stream>>>(x, w_right, w_left, gp, XH, XL, WH, WL, WT2b);
  k_right_feat<<<256, 512, 0, stream>>>(XH, XL, WH, WL, x, norm_a, FT2b);
  k_gemm_mfma<<<256, 512, 0, stream>>>(XH, FT2b, WT2b, outP);
  k_merge<<<256, 256, 0, stream>>>(outP, b_left, out);
}